// Round 1
// baseline (694.926 us; speedup 1.0000x reference)
//
#include <hip/hip_runtime.h>
#include <math.h>

// ---------------------------------------------------------------------------
// OptimizedEdgeEnhancement on MI355X — Round 1: correct fp32 multi-pass
//
// Pipeline: conv1x1(256->64) -> gauss5x5 -> scharr/lap edge -> global-max
// normalize -> SE attention -> conv1x1(64->64).
//
// Pass structure (global max + per-channel mean force a sync point):
//   k0: transpose w_in -> wT[c][o]; zero reduction scratch
//   k1: conv_in GEMM  x[256 MiB] -> y[64 MiB]           (fp32 VALU bound)
//   k2: fused gauss+scharr+lap -> edge_raw[64 MiB], block-reduced
//       global max (atomicMax on uint bits, edge>=0) and per-plane sums
//   k3: SE MLP, folds inv_max*scale into w_eff[b][c][o]
//   k4: out[b,o,p] = sum_c edge_raw[b,c,p]*w_eff[b][c][o] + b_out[o]
//
// clip(edge/(max+1e-8),0,1) is a no-op: edge>=0 and ratio<1 strictly.
// ---------------------------------------------------------------------------

#define HW 65536   // 256*256

// workspace byte offsets
#define WS_WT    0ull                          // 64 KiB  : w_in^T [256][64]
#define WS_Y     65536ull                      // 64 MiB  : y  [4][64][65536]
#define WS_EDGE  (65536ull + 67108864ull)      // 64 MiB  : edge_raw
#define WS_SMALL (65536ull + 134217728ull)     // umax @+0, sums @+64, w_eff @+2048

__global__ __launch_bounds__(256) void k0_prep(const float* __restrict__ w_in,
                                               float* __restrict__ wT,
                                               unsigned* __restrict__ small) {
    const int tid = threadIdx.x;
    for (int i = tid; i < 512; i += 256) small[i] = 0u;  // umax + sums region
    for (int i = tid; i < 64 * 256; i += 256) {
        int o = i >> 8, c = i & 255;
        wT[c * 64 + o] = w_in[i];
    }
}

__global__ __launch_bounds__(256) void k1_convin(const float* __restrict__ x,
                                                 const float* __restrict__ wT,
                                                 const float* __restrict__ b_in,
                                                 float* __restrict__ y) {
    const int blk = blockIdx.x;
    const int b = blk >> 8;                       // 256 blocks per batch
    const int p = ((blk & 255) << 8) + threadIdx.x;
    const float* xb = x + (size_t)b * 256 * HW + p;
    float acc[64];
#pragma unroll
    for (int o = 0; o < 64; ++o) acc[o] = b_in[o];
#pragma unroll 4
    for (int c = 0; c < 256; ++c) {
        float xv = xb[(size_t)c * HW];
        const float* wr = wT + c * 64;            // uniform addr -> s_load
#pragma unroll
        for (int o = 0; o < 64; ++o) acc[o] = fmaf(xv, wr[o], acc[o]);
    }
    float* yb = y + (size_t)b * 64 * HW + p;
#pragma unroll
    for (int o = 0; o < 64; ++o) yb[(size_t)o * HW] = acc[o];
}

__global__ __launch_bounds__(256) void k2_edge(const float* __restrict__ y,
                                               float* __restrict__ edge,
                                               unsigned* __restrict__ umax,
                                               float* __restrict__ sums) {
    const int plane = blockIdx.y;                 // b*64 + c
    const int tx0 = (blockIdx.x & 7) * 32;
    const int ty0 = (blockIdx.x >> 3) * 32;
    const float* yp = y + (size_t)plane * HW;

    __shared__ float yt[38 * 40];                 // y tile + halo 3, lda 40
    __shared__ float st[34 * 36];                 // smoothed tile + halo 1
    __shared__ float red[256];

    const int tid = threadIdx.x;
    for (int i = tid; i < 38 * 38; i += 256) {
        int r = i / 38, cc = i - r * 38;
        int gy = ty0 - 3 + r, gx = tx0 - 3 + cc;
        float v = 0.f;
        if (gy >= 0 && gy < 256 && gx >= 0 && gx < 256) v = yp[gy * 256 + gx];
        yt[r * 40 + cc] = v;
    }
    __syncthreads();

    // gaussian (sigma=2, 5x5), separable weights exp(-d^2/8)
    const float g0c = 0.60653066f, g1c = 0.88249690f;
    const float S1 = 2.f * g0c + 2.f * g1c + 1.f;
    const float inv2 = 1.f / (S1 * S1);
    const float gn[5] = {g0c, g1c, 1.f, g1c, g0c};
    for (int i = tid; i < 34 * 34; i += 256) {
        int r = i / 34, cc = i - r * 34;
        int gy = ty0 - 1 + r, gx = tx0 - 1 + cc;
        float v = 0.f;
        if (gy >= 0 && gy < 256 && gx >= 0 && gx < 256) {
            float s = 0.f;
#pragma unroll
            for (int u = 0; u < 5; ++u) {
                float rs = 0.f;
#pragma unroll
                for (int vv = 0; vv < 5; ++vv)
                    rs = fmaf(gn[vv], yt[(r + u) * 40 + cc + vv], rs);
                s = fmaf(gn[u], rs, s);
            }
            v = s * inv2;
        }
        st[r * 36 + cc] = v;    // zero outside image = zero-padded sm
    }
    __syncthreads();

    float lmax = 0.f, lsum = 0.f;
    for (int i = tid; i < 1024; i += 256) {
        int r = i >> 5, cc = i & 31;
        const float* s0 = st + r * 36 + cc;
        float a00 = s0[0],      a01 = s0[1],      a02 = s0[2];
        float a10 = s0[36],     a11 = s0[37],     a12 = s0[38];
        float a20 = s0[72],     a21 = s0[73],     a22 = s0[74];
        float g0  = 3.f * (a00 - a02) + 10.f * (a10 - a12) + 3.f * (a20 - a22);
        float g90 = 3.f * (a00 - a20) + 10.f * (a01 - a21) + 3.f * (a02 - a22);
        float lap = 4.f * a11 - a01 - a10 - a12 - a21;
        float e = fmaxf(fabsf(g0), fabsf(g90)) + 0.1f * fabsf(lap);
        edge[(size_t)plane * HW + (size_t)(ty0 + r) * 256 + (tx0 + cc)] = e;
        lmax = fmaxf(lmax, e);
        lsum += e;
    }

    red[tid] = lmax;
    __syncthreads();
    for (int s = 128; s > 0; s >>= 1) {
        if (tid < s) red[tid] = fmaxf(red[tid], red[tid + s]);
        __syncthreads();
    }
    if (tid == 0) atomicMax(umax, __float_as_uint(red[0]));  // edge>=0: uint-monotone
    __syncthreads();
    red[tid] = lsum;
    __syncthreads();
    for (int s = 128; s > 0; s >>= 1) {
        if (tid < s) red[tid] += red[tid + s];
        __syncthreads();
    }
    if (tid == 0) atomicAdd(&sums[plane], red[0]);
}

__global__ __launch_bounds__(256) void k3_se(const unsigned* __restrict__ umax,
                                             const float* __restrict__ sums,
                                             const float* __restrict__ w_fc1,
                                             const float* __restrict__ b_fc1,
                                             const float* __restrict__ w_fc2,
                                             const float* __restrict__ b_fc2,
                                             const float* __restrict__ w_out,
                                             float* __restrict__ w_eff) {
    const int tid = threadIdx.x;
    const int b = tid >> 6, o = tid & 63;
    const float mx = __uint_as_float(*umax);
    const float inv = 1.f / (mx + 1e-8f);
    __shared__ float coef[256];                    // scale[b][c] * inv

    float h[4];
#pragma unroll
    for (int j = 0; j < 4; ++j) h[j] = b_fc1[j];
    for (int c = 0; c < 64; ++c) {
        float pooled = sums[b * 64 + c] * inv * (1.f / 65536.f);
#pragma unroll
        for (int j = 0; j < 4; ++j) h[j] = fmaf(pooled, w_fc1[j * 64 + c], h[j]);
    }
#pragma unroll
    for (int j = 0; j < 4; ++j) h[j] = fmaxf(h[j], 0.f);
    float z = b_fc2[o];
#pragma unroll
    for (int j = 0; j < 4; ++j) z = fmaf(h[j], w_fc2[o * 4 + j], z);
    float sc = 1.f / (1.f + expf(-z));
    coef[tid] = sc * inv;
    __syncthreads();
    // w_eff[b][c][o] = w_out[o][c] * coef[b][c]
    for (int c = 0; c < 64; ++c)
        w_eff[((b * 64) + c) * 64 + o] = w_out[o * 64 + c] * coef[b * 64 + c];
}

__global__ __launch_bounds__(256) void k4_out(const float* __restrict__ edge,
                                              const float* __restrict__ w_eff,
                                              const float* __restrict__ b_out,
                                              float* __restrict__ out) {
    const int blk = blockIdx.x;
    const int b = blk >> 8;
    const int p = ((blk & 255) << 8) + threadIdx.x;
    const float* eb = edge + (size_t)b * 64 * HW + p;
    const float* wb = w_eff + b * 4096;
    float acc[64];
#pragma unroll
    for (int o = 0; o < 64; ++o) acc[o] = b_out[o];
#pragma unroll 2
    for (int c = 0; c < 64; ++c) {
        float ev = eb[(size_t)c * HW];
        const float* wr = wb + c * 64;            // uniform addr -> s_load
#pragma unroll
        for (int o = 0; o < 64; ++o) acc[o] = fmaf(ev, wr[o], acc[o]);
    }
    float* ob = out + (size_t)b * 64 * HW + p;
#pragma unroll
    for (int o = 0; o < 64; ++o) ob[(size_t)o * HW] = acc[o];
}

extern "C" void kernel_launch(void* const* d_in, const int* in_sizes, int n_in,
                              void* d_out, int out_size, void* d_ws, size_t ws_size,
                              hipStream_t stream) {
    const float* x     = (const float*)d_in[0];
    const float* w_in  = (const float*)d_in[1];
    const float* b_in  = (const float*)d_in[2];
    const float* w_fc1 = (const float*)d_in[3];
    const float* b_fc1 = (const float*)d_in[4];
    const float* w_fc2 = (const float*)d_in[5];
    const float* b_fc2 = (const float*)d_in[6];
    const float* w_out = (const float*)d_in[7];
    const float* b_out = (const float*)d_in[8];

    char* ws = (char*)d_ws;
    float*    wT    = (float*)(ws + WS_WT);
    float*    y     = (float*)(ws + WS_Y);
    float*    edge  = (float*)(ws + WS_EDGE);
    unsigned* umax  = (unsigned*)(ws + WS_SMALL);
    float*    sums  = (float*)(ws + WS_SMALL + 64);
    float*    w_eff = (float*)(ws + WS_SMALL + 2048);
    float*    out   = (float*)d_out;

    hipLaunchKernelGGL(k0_prep,  dim3(1),        dim3(256), 0, stream, w_in, wT, umax);
    hipLaunchKernelGGL(k1_convin,dim3(1024),     dim3(256), 0, stream, x, wT, b_in, y);
    hipLaunchKernelGGL(k2_edge,  dim3(64, 256),  dim3(256), 0, stream, y, edge, umax, sums);
    hipLaunchKernelGGL(k3_se,    dim3(1),        dim3(256), 0, stream, umax, sums,
                       w_fc1, b_fc1, w_fc2, b_fc2, w_out, w_eff);
    hipLaunchKernelGGL(k4_out,   dim3(1024),     dim3(256), 0, stream, edge, w_eff, b_out, out);
}

// Round 2
// 561.070 us; speedup vs baseline: 1.2386x; 1.2386x over previous
//
#include <hip/hip_runtime.h>
#include <math.h>

// ---------------------------------------------------------------------------
// OptimizedEdgeEnhancement on MI355X — Round 2
//
// R1 post-mortem: all three big passes were ~220 us (VALUBusy ~24%).
//  - k1/k4: weight reads fell out of the scalar path (SGPR pressure at
//    unroll 4: 256 weight floats > 102 SGPRs) -> per-lane VMEM loads, 64
//    memory ops per FMA-group. Fix: weights in LDS, lane = 4 px x 16 outs,
//    per c: 1 global_load_dwordx4 + 4 ds_read_b128 (broadcast/2-way, free)
//    + 64 FMA -> FMA-issue bound.
//  - k2: ~20 barriers/block + 2 LDS round trips -> latency bound. Fix:
//    register-resident separable stencil, 1 wave = 16-row band, horizontal
//    halo via __shfl, no LDS, no barriers, wave-shuffle reductions.
// ---------------------------------------------------------------------------

#define HW 65536   // 256*256

// workspace byte offsets
#define WS_WT    0ull                          // 64 KiB  : w_in^T [256][64]
#define WS_Y     65536ull                      // 64 MiB  : y  [4][64][65536]
#define WS_EDGE  (65536ull + 67108864ull)      // 64 MiB  : edge_raw
#define WS_SMALL (65536ull + 134217728ull)     // umax @+0, sums @+64, w_eff @+2048

__global__ __launch_bounds__(256) void k0_prep(const float* __restrict__ w_in,
                                               float* __restrict__ wT,
                                               unsigned* __restrict__ small) {
    const int tid = threadIdx.x;
    for (int i = tid; i < 512; i += 256) small[i] = 0u;  // umax + sums region
    for (int i = tid; i < 64 * 256; i += 256) {
        int o = i >> 8, c = i & 255;
        wT[c * 64 + o] = w_in[i];
    }
}

// conv1x1 256->64. Block: 256 px, 4 waves. Lane: 4 px (float4) x 16 outputs.
__global__ __launch_bounds__(256) void k1_convin(const float* __restrict__ x,
                                                 const float* __restrict__ wT,
                                                 const float* __restrict__ b_in,
                                                 float* __restrict__ y) {
    __shared__ float ws[64 * 64];                 // one 64-channel chunk of w
    const int tid  = threadIdx.x;
    const int lane = tid & 63;
    const int wv   = tid >> 6;
    const int blk  = blockIdx.x;
    const int b    = blk >> 8;
    const int pbase = ((blk & 255) << 8) + (wv << 6) + ((lane & 15) << 2);
    const int og    = (lane >> 4) << 4;           // 0,16,32,48

    const float* xp = x + (size_t)(b << 8) * HW + pbase;

    float acc[4][16];
#pragma unroll
    for (int oi = 0; oi < 16; ++oi) {
        float bv = b_in[og + oi];
        acc[0][oi] = bv; acc[1][oi] = bv; acc[2][oi] = bv; acc[3][oi] = bv;
    }

    for (int ch = 0; ch < 4; ++ch) {
        __syncthreads();
        const float4* src = (const float4*)(wT + (ch << 6) * 64);
        float4* dst = (float4*)ws;
        for (int i = tid; i < 1024; i += 256) dst[i] = src[i];
        __syncthreads();

        const float* xc = xp + (size_t)(ch << 6) * HW;
#pragma unroll 2
        for (int cc = 0; cc < 64; ++cc) {
            float4 xv = *(const float4*)(xc + (size_t)cc * HW);
            const float* wr = ws + (cc << 6) + og;
            float4 w0 = *(const float4*)(wr);
            float4 w1 = *(const float4*)(wr + 4);
            float4 w2 = *(const float4*)(wr + 8);
            float4 w3 = *(const float4*)(wr + 12);
            float wf[16] = {w0.x,w0.y,w0.z,w0.w, w1.x,w1.y,w1.z,w1.w,
                            w2.x,w2.y,w2.z,w2.w, w3.x,w3.y,w3.z,w3.w};
#pragma unroll
            for (int oi = 0; oi < 16; ++oi) {
                acc[0][oi] = fmaf(xv.x, wf[oi], acc[0][oi]);
                acc[1][oi] = fmaf(xv.y, wf[oi], acc[1][oi]);
                acc[2][oi] = fmaf(xv.z, wf[oi], acc[2][oi]);
                acc[3][oi] = fmaf(xv.w, wf[oi], acc[3][oi]);
            }
        }
    }

    float* yb = y + (size_t)(b << 6) * HW + pbase;
#pragma unroll
    for (int oi = 0; oi < 16; ++oi) {
        float4 o4 = {acc[0][oi], acc[1][oi], acc[2][oi], acc[3][oi]};
        *(float4*)(yb + (size_t)(og + oi) * HW) = o4;
    }
}

// fused gauss5x5 + scharr/lap. 1 wave = one 16-row band of one plane.
// Register stencil, horizontal halo via shuffles; no LDS, no barriers.
__global__ __launch_bounds__(256) void k2_edge(const float* __restrict__ y,
                                               float* __restrict__ edge,
                                               unsigned* __restrict__ umax,
                                               float* __restrict__ sums) {
    const int lane = threadIdx.x & 63;
    const int task = blockIdx.x * 4 + (threadIdx.x >> 6);  // 4096 tasks
    const int plane = task >> 4;
    const int r0 = (task & 15) << 4;
    const float* yp = y + (size_t)plane * HW;
    float* ep = edge + (size_t)plane * HW;
    const int col4 = lane << 2;

    const float g = 0.60653066f, G = 0.88249690f;
    const float S1 = 2.f * g + 2.f * G + 1.f;
    const float inv2 = 1.f / (S1 * S1);

    float4 h0{}, h1{}, h2{}, h3{}, h4{};
    float4 s0{}, s1{}, s2{};
    float lmax = 0.f, lsum = 0.f;

    for (int j = r0 - 3; j <= r0 + 18; ++j) {
        float4 v = {0.f, 0.f, 0.f, 0.f};
        if (j >= 0 && j < 256) v = *(const float4*)(yp + j * 256 + col4);
        // horizontal gaussian (zero pad at columns)
        float lz = __shfl(v.z, lane - 1), lw = __shfl(v.w, lane - 1);
        float rx = __shfl(v.x, lane + 1), ry = __shfl(v.y, lane + 1);
        if (lane == 0)  { lz = 0.f; lw = 0.f; }
        if (lane == 63) { rx = 0.f; ry = 0.f; }
        float4 hv;
        hv.x = fmaf(g, lz,  fmaf(G, lw,  fmaf(G, v.y, fmaf(g, v.z, v.x))));
        hv.y = fmaf(g, lw,  fmaf(G, v.x, fmaf(G, v.z, fmaf(g, v.w, v.y))));
        hv.z = fmaf(g, v.x, fmaf(G, v.y, fmaf(G, v.w, fmaf(g, rx, v.z))));
        hv.w = fmaf(g, v.y, fmaf(G, v.z, fmaf(G, rx,  fmaf(g, ry, v.w))));
        h0 = h1; h1 = h2; h2 = h3; h3 = h4; h4 = hv;

        if (j >= r0 + 1) {
            // vertical gaussian -> smoothed row m = j-2
            float4 sv;
            sv.x = (g * (h0.x + h4.x) + G * (h1.x + h3.x) + h2.x) * inv2;
            sv.y = (g * (h0.y + h4.y) + G * (h1.y + h3.y) + h2.y) * inv2;
            sv.z = (g * (h0.z + h4.z) + G * (h1.z + h3.z) + h2.z) * inv2;
            sv.w = (g * (h0.w + h4.w) + G * (h1.w + h3.w) + h2.w) * inv2;
            s0 = s1; s1 = s2; s2 = sv;

            if (j >= r0 + 3) {
                const int er = j - 3;            // edge row in [r0, r0+15]
                float4 A = s0, B = s1, C = s2;   // rows er-1, er, er+1 of sm
                float Alw = __shfl(A.w, lane - 1), Arx = __shfl(A.x, lane + 1);
                float Blw = __shfl(B.w, lane - 1), Brx = __shfl(B.x, lane + 1);
                float Clw = __shfl(C.w, lane - 1), Crx = __shfl(C.x, lane + 1);
                if (lane == 0)  { Alw = 0.f; Blw = 0.f; Clw = 0.f; }
                if (lane == 63) { Arx = 0.f; Brx = 0.f; Crx = 0.f; }
                if (er == 0)   { A = float4{}; Alw = 0.f; Arx = 0.f; }  // sm zero-pad
                if (er == 255) { C = float4{}; Clw = 0.f; Crx = 0.f; }
                float A6[6] = {Alw, A.x, A.y, A.z, A.w, Arx};
                float B6[6] = {Blw, B.x, B.y, B.z, B.w, Brx};
                float C6[6] = {Clw, C.x, C.y, C.z, C.w, Crx};
                float4 e4;
                float* ev = (float*)&e4;
#pragma unroll
                for (int k = 0; k < 4; ++k) {
                    float g0  = 3.f * (A6[k] - A6[k+2]) + 10.f * (B6[k] - B6[k+2])
                              + 3.f * (C6[k] - C6[k+2]);
                    float g90 = 3.f * (A6[k] - C6[k]) + 10.f * (A6[k+1] - C6[k+1])
                              + 3.f * (A6[k+2] - C6[k+2]);
                    float lap = 4.f * B6[k+1] - B6[k] - B6[k+2] - A6[k+1] - C6[k+1];
                    float e = fmaxf(fabsf(g0), fabsf(g90)) + 0.1f * fabsf(lap);
                    ev[k] = e;
                    lmax = fmaxf(lmax, e);
                    lsum += e;
                }
                *(float4*)(ep + er * 256 + col4) = e4;
            }
        }
    }

    for (int off = 32; off > 0; off >>= 1) {
        lmax = fmaxf(lmax, __shfl_down(lmax, off));
        lsum += __shfl_down(lsum, off);
    }
    if (lane == 0) {
        atomicMax(umax, __float_as_uint(lmax));  // edge>=0: uint-order == float-order
        atomicAdd(&sums[plane], lsum);
    }
}

__global__ __launch_bounds__(256) void k3_se(const unsigned* __restrict__ umax,
                                             const float* __restrict__ sums,
                                             const float* __restrict__ w_fc1,
                                             const float* __restrict__ b_fc1,
                                             const float* __restrict__ w_fc2,
                                             const float* __restrict__ b_fc2,
                                             const float* __restrict__ w_out,
                                             float* __restrict__ w_eff) {
    const int tid = threadIdx.x;
    const int b = tid >> 6, o = tid & 63;
    const float mx = __uint_as_float(*umax);
    const float inv = 1.f / (mx + 1e-8f);
    __shared__ float coef[256];                    // scale[b][c] * inv

    float h[4];
#pragma unroll
    for (int j = 0; j < 4; ++j) h[j] = b_fc1[j];
    for (int c = 0; c < 64; ++c) {
        float pooled = sums[b * 64 + c] * inv * (1.f / 65536.f);
#pragma unroll
        for (int j = 0; j < 4; ++j) h[j] = fmaf(pooled, w_fc1[j * 64 + c], h[j]);
    }
#pragma unroll
    for (int j = 0; j < 4; ++j) h[j] = fmaxf(h[j], 0.f);
    float z = b_fc2[o];
#pragma unroll
    for (int j = 0; j < 4; ++j) z = fmaf(h[j], w_fc2[o * 4 + j], z);
    float sc = 1.f / (1.f + expf(-z));
    coef[tid] = sc * inv;
    __syncthreads();
    // w_eff[b][c][o] = w_out[o][c] * coef[b][c]
    for (int c = 0; c < 64; ++c)
        w_eff[((b * 64) + c) * 64 + o] = w_out[o * 64 + c] * coef[b * 64 + c];
}

// conv1x1 64->64 with per-batch folded weights. Same skeleton as k1.
__global__ __launch_bounds__(256) void k4_out(const float* __restrict__ edge,
                                              const float* __restrict__ w_eff,
                                              const float* __restrict__ b_out,
                                              float* __restrict__ out) {
    __shared__ float ws[64 * 64];
    const int tid  = threadIdx.x;
    const int lane = tid & 63;
    const int wv   = tid >> 6;
    const int blk  = blockIdx.x;
    const int b    = blk >> 8;
    const int pbase = ((blk & 255) << 8) + (wv << 6) + ((lane & 15) << 2);
    const int og    = (lane >> 4) << 4;

    {
        const float4* src = (const float4*)(w_eff + b * 4096);
        float4* dst = (float4*)ws;
        for (int i = tid; i < 1024; i += 256) dst[i] = src[i];
    }
    __syncthreads();

    const float* eb = edge + (size_t)(b << 6) * HW + pbase;
    float acc[4][16];
#pragma unroll
    for (int oi = 0; oi < 16; ++oi) {
        float bv = b_out[og + oi];
        acc[0][oi] = bv; acc[1][oi] = bv; acc[2][oi] = bv; acc[3][oi] = bv;
    }

#pragma unroll 2
    for (int cc = 0; cc < 64; ++cc) {
        float4 ev = *(const float4*)(eb + (size_t)cc * HW);
        const float* wr = ws + (cc << 6) + og;
        float4 w0 = *(const float4*)(wr);
        float4 w1 = *(const float4*)(wr + 4);
        float4 w2 = *(const float4*)(wr + 8);
        float4 w3 = *(const float4*)(wr + 12);
        float wf[16] = {w0.x,w0.y,w0.z,w0.w, w1.x,w1.y,w1.z,w1.w,
                        w2.x,w2.y,w2.z,w2.w, w3.x,w3.y,w3.z,w3.w};
#pragma unroll
        for (int oi = 0; oi < 16; ++oi) {
            acc[0][oi] = fmaf(ev.x, wf[oi], acc[0][oi]);
            acc[1][oi] = fmaf(ev.y, wf[oi], acc[1][oi]);
            acc[2][oi] = fmaf(ev.z, wf[oi], acc[2][oi]);
            acc[3][oi] = fmaf(ev.w, wf[oi], acc[3][oi]);
        }
    }

    float* ob = out + (size_t)(b << 6) * HW + pbase;
#pragma unroll
    for (int oi = 0; oi < 16; ++oi) {
        float4 o4 = {acc[0][oi], acc[1][oi], acc[2][oi], acc[3][oi]};
        *(float4*)(ob + (size_t)(og + oi) * HW) = o4;
    }
}

extern "C" void kernel_launch(void* const* d_in, const int* in_sizes, int n_in,
                              void* d_out, int out_size, void* d_ws, size_t ws_size,
                              hipStream_t stream) {
    const float* x     = (const float*)d_in[0];
    const float* w_in  = (const float*)d_in[1];
    const float* b_in  = (const float*)d_in[2];
    const float* w_fc1 = (const float*)d_in[3];
    const float* b_fc1 = (const float*)d_in[4];
    const float* w_fc2 = (const float*)d_in[5];
    const float* b_fc2 = (const float*)d_in[6];
    const float* w_out = (const float*)d_in[7];
    const float* b_out = (const float*)d_in[8];

    char* ws = (char*)d_ws;
    float*    wT    = (float*)(ws + WS_WT);
    float*    y     = (float*)(ws + WS_Y);
    float*    edge  = (float*)(ws + WS_EDGE);
    unsigned* umax  = (unsigned*)(ws + WS_SMALL);
    float*    sums  = (float*)(ws + WS_SMALL + 64);
    float*    w_eff = (float*)(ws + WS_SMALL + 2048);
    float*    out   = (float*)d_out;

    hipLaunchKernelGGL(k0_prep,  dim3(1),    dim3(256), 0, stream, w_in, wT, umax);
    hipLaunchKernelGGL(k1_convin,dim3(1024), dim3(256), 0, stream, x, wT, b_in, y);
    hipLaunchKernelGGL(k2_edge,  dim3(1024), dim3(256), 0, stream, y, edge, umax, sums);
    hipLaunchKernelGGL(k3_se,    dim3(1),    dim3(256), 0, stream, umax, sums,
                       w_fc1, b_fc1, w_fc2, b_fc2, w_out, w_eff);
    hipLaunchKernelGGL(k4_out,   dim3(1024), dim3(256), 0, stream, edge, w_eff, b_out, out);
}

// Round 3
// 558.368 us; speedup vs baseline: 1.2446x; 1.0048x over previous
//
#include <hip/hip_runtime.h>
#include <math.h>

// ---------------------------------------------------------------------------
// OptimizedEdgeEnhancement on MI355X — Round 3
//
// R2 post-mortem: k1 = 160 us at VALUBusy 44.6%, FETCH 134 MB (x half
// L3-resident). Limiter: per cc, one dependent x float4 load (~400 cyc
// L2/L3 latency) feeding 64 FMAs (128 cyc); unroll-2 gives ~40% duty
// cycle == measured 44%. Fix: explicit prefetch ring of depth 4 channels
// so 4 loads are always in flight over 512 FMA cycles. Same for k4.
// Loops kept rolled (body ~2.2 KB) to stay inside the 32 KB I$.
// Numerically identical to R2.
// ---------------------------------------------------------------------------

#define HW 65536   // 256*256

// workspace byte offsets
#define WS_WT    0ull                          // 64 KiB  : w_in^T [256][64]
#define WS_Y     65536ull                      // 64 MiB  : y  [4][64][65536]
#define WS_EDGE  (65536ull + 67108864ull)      // 64 MiB  : edge_raw
#define WS_SMALL (65536ull + 134217728ull)     // umax @+0, sums @+64, w_eff @+2048

__global__ __launch_bounds__(256) void k0_prep(const float* __restrict__ w_in,
                                               float* __restrict__ wT,
                                               unsigned* __restrict__ small) {
    const int tid = threadIdx.x;
    for (int i = tid; i < 512; i += 256) small[i] = 0u;  // umax + sums region
    for (int i = tid; i < 64 * 256; i += 256) {
        int o = i >> 8, c = i & 255;
        wT[c * 64 + o] = w_in[i];
    }
}

// 64 FMAs of one channel-row against the acc tile
#define K1_COMP(xv, wrp)                                                      \
    {                                                                         \
        float4 w0 = *(const float4*)(wrp);                                    \
        float4 w1 = *(const float4*)((wrp) + 4);                              \
        float4 w2 = *(const float4*)((wrp) + 8);                              \
        float4 w3 = *(const float4*)((wrp) + 12);                             \
        float wf[16] = {w0.x,w0.y,w0.z,w0.w, w1.x,w1.y,w1.z,w1.w,             \
                        w2.x,w2.y,w2.z,w2.w, w3.x,w3.y,w3.z,w3.w};            \
        _Pragma("unroll")                                                     \
        for (int oi = 0; oi < 16; ++oi) {                                     \
            acc[0][oi] = fmaf((xv).x, wf[oi], acc[0][oi]);                    \
            acc[1][oi] = fmaf((xv).y, wf[oi], acc[1][oi]);                    \
            acc[2][oi] = fmaf((xv).z, wf[oi], acc[2][oi]);                    \
            acc[3][oi] = fmaf((xv).w, wf[oi], acc[3][oi]);                    \
        }                                                                     \
    }

// conv1x1 256->64. Block: 256 px, 4 waves. Lane: 4 px (float4) x 16 outputs.
// x loads prefetched 4 channels ahead; weights staged in LDS per 64-ch chunk.
__global__ __launch_bounds__(256) void k1_convin(const float* __restrict__ x,
                                                 const float* __restrict__ wT,
                                                 const float* __restrict__ b_in,
                                                 float* __restrict__ y) {
    __shared__ float ws[64 * 64];                 // one 64-channel chunk of w
    const int tid  = threadIdx.x;
    const int lane = tid & 63;
    const int wv   = tid >> 6;
    const int blk  = blockIdx.x;
    const int b    = blk >> 8;
    const int pbase = ((blk & 255) << 8) + (wv << 6) + ((lane & 15) << 2);
    const int og    = (lane >> 4) << 4;           // 0,16,32,48

    const float* xp = x + (size_t)(b << 8) * HW + pbase;

    float acc[4][16];
#pragma unroll
    for (int oi = 0; oi < 16; ++oi) {
        float bv = b_in[og + oi];
        acc[0][oi] = bv; acc[1][oi] = bv; acc[2][oi] = bv; acc[3][oi] = bv;
    }

    // prime prefetch ring: channels 0..3
    float4 xb0 = *(const float4*)(xp + 0 * (size_t)HW);
    float4 xb1 = *(const float4*)(xp + 1 * (size_t)HW);
    float4 xb2 = *(const float4*)(xp + 2 * (size_t)HW);
    float4 xb3 = *(const float4*)(xp + 3 * (size_t)HW);

#pragma unroll 1
    for (int ch = 0; ch < 4; ++ch) {
        __syncthreads();
        const float4* src = (const float4*)(wT + (ch << 6) * 64);
        float4* dst = (float4*)ws;
        for (int i = tid; i < 1024; i += 256) dst[i] = src[i];
        __syncthreads();

#pragma unroll 1
        for (int cc = 0; cc < 64; cc += 4) {
            const int gn = ((ch << 6) + cc + 4) & 255;   // wraps to 0..3 at tail
            float4 n0 = *(const float4*)(xp + (size_t)(gn    ) * HW);
            float4 n1 = *(const float4*)(xp + (size_t)(gn + 1) * HW);
            float4 n2 = *(const float4*)(xp + (size_t)(gn + 2) * HW);
            float4 n3 = *(const float4*)(xp + (size_t)(gn + 3) * HW);

            const float* wr = ws + (cc << 6) + og;
            K1_COMP(xb0, wr);
            K1_COMP(xb1, wr + 64);
            K1_COMP(xb2, wr + 128);
            K1_COMP(xb3, wr + 192);

            xb0 = n0; xb1 = n1; xb2 = n2; xb3 = n3;
        }
    }

    float* yb = y + (size_t)(b << 6) * HW + pbase;
#pragma unroll
    for (int oi = 0; oi < 16; ++oi) {
        float4 o4 = {acc[0][oi], acc[1][oi], acc[2][oi], acc[3][oi]};
        *(float4*)(yb + (size_t)(og + oi) * HW) = o4;
    }
}

// fused gauss5x5 + scharr/lap. 1 wave = one 16-row band of one plane.
// Register stencil, horizontal halo via shuffles; no LDS, no barriers.
__global__ __launch_bounds__(256) void k2_edge(const float* __restrict__ y,
                                               float* __restrict__ edge,
                                               unsigned* __restrict__ umax,
                                               float* __restrict__ sums) {
    const int lane = threadIdx.x & 63;
    const int task = blockIdx.x * 4 + (threadIdx.x >> 6);  // 4096 tasks
    const int plane = task >> 4;
    const int r0 = (task & 15) << 4;
    const float* yp = y + (size_t)plane * HW;
    float* ep = edge + (size_t)plane * HW;
    const int col4 = lane << 2;

    const float g = 0.60653066f, G = 0.88249690f;
    const float S1 = 2.f * g + 2.f * G + 1.f;
    const float inv2 = 1.f / (S1 * S1);

    float4 h0{}, h1{}, h2{}, h3{}, h4{};
    float4 s0{}, s1{}, s2{};
    float lmax = 0.f, lsum = 0.f;

    for (int j = r0 - 3; j <= r0 + 18; ++j) {
        float4 v = {0.f, 0.f, 0.f, 0.f};
        if (j >= 0 && j < 256) v = *(const float4*)(yp + j * 256 + col4);
        // horizontal gaussian (zero pad at columns)
        float lz = __shfl(v.z, lane - 1), lw = __shfl(v.w, lane - 1);
        float rx = __shfl(v.x, lane + 1), ry = __shfl(v.y, lane + 1);
        if (lane == 0)  { lz = 0.f; lw = 0.f; }
        if (lane == 63) { rx = 0.f; ry = 0.f; }
        float4 hv;
        hv.x = fmaf(g, lz,  fmaf(G, lw,  fmaf(G, v.y, fmaf(g, v.z, v.x))));
        hv.y = fmaf(g, lw,  fmaf(G, v.x, fmaf(G, v.z, fmaf(g, v.w, v.y))));
        hv.z = fmaf(g, v.x, fmaf(G, v.y, fmaf(G, v.w, fmaf(g, rx, v.z))));
        hv.w = fmaf(g, v.y, fmaf(G, v.z, fmaf(G, rx,  fmaf(g, ry, v.w))));
        h0 = h1; h1 = h2; h2 = h3; h3 = h4; h4 = hv;

        if (j >= r0 + 1) {
            // vertical gaussian -> smoothed row m = j-2
            float4 sv;
            sv.x = (g * (h0.x + h4.x) + G * (h1.x + h3.x) + h2.x) * inv2;
            sv.y = (g * (h0.y + h4.y) + G * (h1.y + h3.y) + h2.y) * inv2;
            sv.z = (g * (h0.z + h4.z) + G * (h1.z + h3.z) + h2.z) * inv2;
            sv.w = (g * (h0.w + h4.w) + G * (h1.w + h3.w) + h2.w) * inv2;
            s0 = s1; s1 = s2; s2 = sv;

            if (j >= r0 + 3) {
                const int er = j - 3;            // edge row in [r0, r0+15]
                float4 A = s0, B = s1, C = s2;   // rows er-1, er, er+1 of sm
                float Alw = __shfl(A.w, lane - 1), Arx = __shfl(A.x, lane + 1);
                float Blw = __shfl(B.w, lane - 1), Brx = __shfl(B.x, lane + 1);
                float Clw = __shfl(C.w, lane - 1), Crx = __shfl(C.x, lane + 1);
                if (lane == 0)  { Alw = 0.f; Blw = 0.f; Clw = 0.f; }
                if (lane == 63) { Arx = 0.f; Brx = 0.f; Crx = 0.f; }
                if (er == 0)   { A = float4{}; Alw = 0.f; Arx = 0.f; }  // sm zero-pad
                if (er == 255) { C = float4{}; Clw = 0.f; Crx = 0.f; }
                float A6[6] = {Alw, A.x, A.y, A.z, A.w, Arx};
                float B6[6] = {Blw, B.x, B.y, B.z, B.w, Brx};
                float C6[6] = {Clw, C.x, C.y, C.z, C.w, Crx};
                float4 e4;
                float* ev = (float*)&e4;
#pragma unroll
                for (int k = 0; k < 4; ++k) {
                    float g0  = 3.f * (A6[k] - A6[k+2]) + 10.f * (B6[k] - B6[k+2])
                              + 3.f * (C6[k] - C6[k+2]);
                    float g90 = 3.f * (A6[k] - C6[k]) + 10.f * (A6[k+1] - C6[k+1])
                              + 3.f * (A6[k+2] - C6[k+2]);
                    float lap = 4.f * B6[k+1] - B6[k] - B6[k+2] - A6[k+1] - C6[k+1];
                    float e = fmaxf(fabsf(g0), fabsf(g90)) + 0.1f * fabsf(lap);
                    ev[k] = e;
                    lmax = fmaxf(lmax, e);
                    lsum += e;
                }
                *(float4*)(ep + er * 256 + col4) = e4;
            }
        }
    }

    for (int off = 32; off > 0; off >>= 1) {
        lmax = fmaxf(lmax, __shfl_down(lmax, off));
        lsum += __shfl_down(lsum, off);
    }
    if (lane == 0) {
        atomicMax(umax, __float_as_uint(lmax));  // edge>=0: uint-order == float-order
        atomicAdd(&sums[plane], lsum);
    }
}

__global__ __launch_bounds__(256) void k3_se(const unsigned* __restrict__ umax,
                                             const float* __restrict__ sums,
                                             const float* __restrict__ w_fc1,
                                             const float* __restrict__ b_fc1,
                                             const float* __restrict__ w_fc2,
                                             const float* __restrict__ b_fc2,
                                             const float* __restrict__ w_out,
                                             float* __restrict__ w_eff) {
    const int tid = threadIdx.x;
    const int b = tid >> 6, o = tid & 63;
    const float mx = __uint_as_float(*umax);
    const float inv = 1.f / (mx + 1e-8f);
    __shared__ float coef[256];                    // scale[b][c] * inv

    float h[4];
#pragma unroll
    for (int j = 0; j < 4; ++j) h[j] = b_fc1[j];
    for (int c = 0; c < 64; ++c) {
        float pooled = sums[b * 64 + c] * inv * (1.f / 65536.f);
#pragma unroll
        for (int j = 0; j < 4; ++j) h[j] = fmaf(pooled, w_fc1[j * 64 + c], h[j]);
    }
#pragma unroll
    for (int j = 0; j < 4; ++j) h[j] = fmaxf(h[j], 0.f);
    float z = b_fc2[o];
#pragma unroll
    for (int j = 0; j < 4; ++j) z = fmaf(h[j], w_fc2[o * 4 + j], z);
    float sc = 1.f / (1.f + expf(-z));
    coef[tid] = sc * inv;
    __syncthreads();
    // w_eff[b][c][o] = w_out[o][c] * coef[b][c]
    for (int c = 0; c < 64; ++c)
        w_eff[((b * 64) + c) * 64 + o] = w_out[o * 64 + c] * coef[b * 64 + c];
}

// conv1x1 64->64 with per-batch folded weights; prefetch ring depth 4.
__global__ __launch_bounds__(256) void k4_out(const float* __restrict__ edge,
                                              const float* __restrict__ w_eff,
                                              const float* __restrict__ b_out,
                                              float* __restrict__ out) {
    __shared__ float ws[64 * 64];
    const int tid  = threadIdx.x;
    const int lane = tid & 63;
    const int wv   = tid >> 6;
    const int blk  = blockIdx.x;
    const int b    = blk >> 8;
    const int pbase = ((blk & 255) << 8) + (wv << 6) + ((lane & 15) << 2);
    const int og    = (lane >> 4) << 4;

    {
        const float4* src = (const float4*)(w_eff + b * 4096);
        float4* dst = (float4*)ws;
        for (int i = tid; i < 1024; i += 256) dst[i] = src[i];
    }

    const float* eb = edge + (size_t)(b << 6) * HW + pbase;
    float acc[4][16];
#pragma unroll
    for (int oi = 0; oi < 16; ++oi) {
        float bv = b_out[og + oi];
        acc[0][oi] = bv; acc[1][oi] = bv; acc[2][oi] = bv; acc[3][oi] = bv;
    }

    float4 xb0 = *(const float4*)(eb + 0 * (size_t)HW);
    float4 xb1 = *(const float4*)(eb + 1 * (size_t)HW);
    float4 xb2 = *(const float4*)(eb + 2 * (size_t)HW);
    float4 xb3 = *(const float4*)(eb + 3 * (size_t)HW);

    __syncthreads();

#pragma unroll 1
    for (int cc = 0; cc < 64; cc += 4) {
        const int gn = (cc + 4) & 63;                // wraps at tail
        float4 n0 = *(const float4*)(eb + (size_t)(gn    ) * HW);
        float4 n1 = *(const float4*)(eb + (size_t)(gn + 1) * HW);
        float4 n2 = *(const float4*)(eb + (size_t)(gn + 2) * HW);
        float4 n3 = *(const float4*)(eb + (size_t)(gn + 3) * HW);

        const float* wr = ws + (cc << 6) + og;
        K1_COMP(xb0, wr);
        K1_COMP(xb1, wr + 64);
        K1_COMP(xb2, wr + 128);
        K1_COMP(xb3, wr + 192);

        xb0 = n0; xb1 = n1; xb2 = n2; xb3 = n3;
    }

    float* ob = out + (size_t)(b << 6) * HW + pbase;
#pragma unroll
    for (int oi = 0; oi < 16; ++oi) {
        float4 o4 = {acc[0][oi], acc[1][oi], acc[2][oi], acc[3][oi]};
        *(float4*)(ob + (size_t)(og + oi) * HW) = o4;
    }
}

extern "C" void kernel_launch(void* const* d_in, const int* in_sizes, int n_in,
                              void* d_out, int out_size, void* d_ws, size_t ws_size,
                              hipStream_t stream) {
    const float* x     = (const float*)d_in[0];
    const float* w_in  = (const float*)d_in[1];
    const float* b_in  = (const float*)d_in[2];
    const float* w_fc1 = (const float*)d_in[3];
    const float* b_fc1 = (const float*)d_in[4];
    const float* w_fc2 = (const float*)d_in[5];
    const float* b_fc2 = (const float*)d_in[6];
    const float* w_out = (const float*)d_in[7];
    const float* b_out = (const float*)d_in[8];

    char* ws = (char*)d_ws;
    float*    wT    = (float*)(ws + WS_WT);
    float*    y     = (float*)(ws + WS_Y);
    float*    edge  = (float*)(ws + WS_EDGE);
    unsigned* umax  = (unsigned*)(ws + WS_SMALL);
    float*    sums  = (float*)(ws + WS_SMALL + 64);
    float*    w_eff = (float*)(ws + WS_SMALL + 2048);
    float*    out   = (float*)d_out;

    hipLaunchKernelGGL(k0_prep,  dim3(1),    dim3(256), 0, stream, w_in, wT, umax);
    hipLaunchKernelGGL(k1_convin,dim3(1024), dim3(256), 0, stream, x, wT, b_in, y);
    hipLaunchKernelGGL(k2_edge,  dim3(1024), dim3(256), 0, stream, y, edge, umax, sums);
    hipLaunchKernelGGL(k3_se,    dim3(1),    dim3(256), 0, stream, umax, sums,
                       w_fc1, b_fc1, w_fc2, b_fc2, w_out, w_eff);
    hipLaunchKernelGGL(k4_out,   dim3(1024), dim3(256), 0, stream, edge, w_eff, b_out, out);
}

// Round 5
// 496.500 us; speedup vs baseline: 1.3996x; 1.1246x over previous
//
#include <hip/hip_runtime.h>
#include <math.h>

// ---------------------------------------------------------------------------
// OptimizedEdgeEnhancement on MI355X — Round 5 (R4 design, compile fixed)
//
// R3 post-mortem: x-prefetch ring was NEUTRAL -> k1 is not vmcnt-bound.
// R2 k1 row (VGPR 56, VALUBusy 44%, LDS 16 KB) says acc lives in AGPRs and
// the stall is the 16 ds_read_b128 + lgkmcnt waits per 4-channel group.
// Fix: wave-uniform output group -> weights via s_load into SGPRs
// (v_fma v,s,v), no LDS, no barriers. x keeps an 8-deep ring.
// k2: atomicMax on ONE address from 4096 waves could serialize -> per-task
// scratch results, reduced in k3. Row-ahead prefetch in the stencil loop.
// ---------------------------------------------------------------------------

#define HW 65536   // 256*256

// workspace byte offsets
#define WS_WT    0ull                          // 64 KiB  : w_in^T [256][64]
#define WS_Y     65536ull                      // 64 MiB  : y  [4][64][65536]
#define WS_EDGE  (65536ull + 67108864ull)      // 64 MiB  : edge_raw
#define WS_SMALL (65536ull + 134217728ull)     // wavemax[4096], wavesum[4096], w_eff

__global__ __launch_bounds__(256) void k0_prep(const float* __restrict__ w_in,
                                               float* __restrict__ wT) {
    const int tid = threadIdx.x;
    for (int i = tid; i < 64 * 256; i += 256) {
        int o = i >> 8, c = i & 255;
        wT[c * 64 + o] = w_in[i];
    }
}

// 64 FMAs for one channel: weights from wave-uniform address (s_load),
// xv = 4 pixels, acc[4][16] = 4 px x 16 outputs.
#define CH_COMP(xv, wrow)                                                     \
    {                                                                         \
        float4 w0 = *(const float4*)(wrow);                                   \
        float4 w1 = *(const float4*)((wrow) + 4);                             \
        float4 w2 = *(const float4*)((wrow) + 8);                             \
        float4 w3 = *(const float4*)((wrow) + 12);                            \
        float wf[16] = {w0.x,w0.y,w0.z,w0.w, w1.x,w1.y,w1.z,w1.w,             \
                        w2.x,w2.y,w2.z,w2.w, w3.x,w3.y,w3.z,w3.w};            \
        _Pragma("unroll")                                                     \
        for (int oi = 0; oi < 16; ++oi) {                                     \
            acc[0][oi] = fmaf((xv).x, wf[oi], acc[0][oi]);                    \
            acc[1][oi] = fmaf((xv).y, wf[oi], acc[1][oi]);                    \
            acc[2][oi] = fmaf((xv).z, wf[oi], acc[2][oi]);                    \
            acc[3][oi] = fmaf((xv).w, wf[oi], acc[3][oi]);                    \
        }                                                                     \
    }

// conv1x1 256->64. Block: 256 px. Wave wv: all 256 px x outputs [16wv,16wv+16).
// Lane: 4 px (float4). Weights s_loaded (wave-uniform); x ring depth 8.
__global__ __launch_bounds__(256) void k1_convin(const float* __restrict__ x,
                                                 const float* __restrict__ wT,
                                                 const float* __restrict__ b_in,
                                                 float* __restrict__ y) {
    const int tid  = threadIdx.x;
    const int lane = tid & 63;
    const int og   = __builtin_amdgcn_readfirstlane((tid >> 6) << 4); // 0,16,32,48
    const int blk  = blockIdx.x;
    const int b    = blk >> 8;
    const int px   = ((blk & 255) << 8) + (lane << 2);

    const float* xp  = x + (size_t)(b << 8) * HW + px;
    const float* wTg = wT + og;                   // uniform base

    float acc[4][16];
#pragma unroll
    for (int oi = 0; oi < 16; ++oi) {
        float bv = b_in[og + oi];
        acc[0][oi] = bv; acc[1][oi] = bv; acc[2][oi] = bv; acc[3][oi] = bv;
    }

    float4 xr0 = *(const float4*)(xp + 0 * (size_t)HW);
    float4 xr1 = *(const float4*)(xp + 1 * (size_t)HW);
    float4 xr2 = *(const float4*)(xp + 2 * (size_t)HW);
    float4 xr3 = *(const float4*)(xp + 3 * (size_t)HW);
    float4 xr4 = *(const float4*)(xp + 4 * (size_t)HW);
    float4 xr5 = *(const float4*)(xp + 5 * (size_t)HW);
    float4 xr6 = *(const float4*)(xp + 6 * (size_t)HW);
    float4 xr7 = *(const float4*)(xp + 7 * (size_t)HW);

#pragma unroll 1
    for (int cc = 0; cc < 256; cc += 8) {
        {   // prefetch cc+8..cc+11 (wraps harmlessly at tail)
            const int gn = (cc + 8) & 255;
            float4 n0 = *(const float4*)(xp + (size_t)(gn    ) * HW);
            float4 n1 = *(const float4*)(xp + (size_t)(gn + 1) * HW);
            float4 n2 = *(const float4*)(xp + (size_t)(gn + 2) * HW);
            float4 n3 = *(const float4*)(xp + (size_t)(gn + 3) * HW);
            CH_COMP(xr0, wTg + (size_t)(cc    ) * 64);
            CH_COMP(xr1, wTg + (size_t)(cc + 1) * 64);
            CH_COMP(xr2, wTg + (size_t)(cc + 2) * 64);
            CH_COMP(xr3, wTg + (size_t)(cc + 3) * 64);
            xr0 = n0; xr1 = n1; xr2 = n2; xr3 = n3;
        }
        {   // prefetch cc+12..cc+15
            const int gn = (cc + 12) & 255;
            float4 n0 = *(const float4*)(xp + (size_t)(gn    ) * HW);
            float4 n1 = *(const float4*)(xp + (size_t)(gn + 1) * HW);
            float4 n2 = *(const float4*)(xp + (size_t)(gn + 2) * HW);
            float4 n3 = *(const float4*)(xp + (size_t)(gn + 3) * HW);
            CH_COMP(xr4, wTg + (size_t)(cc + 4) * 64);
            CH_COMP(xr5, wTg + (size_t)(cc + 5) * 64);
            CH_COMP(xr6, wTg + (size_t)(cc + 6) * 64);
            CH_COMP(xr7, wTg + (size_t)(cc + 7) * 64);
            xr4 = n0; xr5 = n1; xr6 = n2; xr7 = n3;
        }
    }

    float* yb = y + (size_t)(b << 6) * HW + px;
#pragma unroll
    for (int oi = 0; oi < 16; ++oi)
        *(float4*)(yb + (size_t)(og + oi) * HW) = float4{acc[0][oi], acc[1][oi],
                                                         acc[2][oi], acc[3][oi]};
}

// fused gauss5x5 + scharr/lap. 1 wave = one 16-row band of one plane.
// Register stencil, horizontal halo via shuffles; no LDS, no barriers,
// no global atomics (per-task scratch results).
__global__ __launch_bounds__(256) void k2_edge(const float* __restrict__ y,
                                               float* __restrict__ edge,
                                               float* __restrict__ wavemax,
                                               float* __restrict__ wavesum) {
    const int lane = threadIdx.x & 63;
    const int task = blockIdx.x * 4 + (threadIdx.x >> 6);  // 4096 tasks
    const int plane = task >> 4;
    const int r0 = (task & 15) << 4;
    const float* yp = y + (size_t)plane * HW;
    float* ep = edge + (size_t)plane * HW;
    const int col4 = lane << 2;

    const float g = 0.60653066f, G = 0.88249690f;
    const float S1 = 2.f * g + 2.f * G + 1.f;
    const float inv2 = 1.f / (S1 * S1);

    float4 h0{}, h1{}, h2{}, h3{}, h4{};
    float4 s0{}, s1{}, s2{};
    float lmax = 0.f, lsum = 0.f;

    float4 vcur{};
    if (r0 - 3 >= 0) vcur = *(const float4*)(yp + (r0 - 3) * 256 + col4);

    for (int j = r0 - 3; j <= r0 + 18; ++j) {
        // prefetch row j+1
        float4 vnext{};
        const int jn = j + 1;
        if (jn <= r0 + 18 && jn >= 0 && jn < 256)
            vnext = *(const float4*)(yp + jn * 256 + col4);
        float4 v = vcur;
        // horizontal gaussian (zero pad at columns)
        float lz = __shfl(v.z, lane - 1), lw = __shfl(v.w, lane - 1);
        float rx = __shfl(v.x, lane + 1), ry = __shfl(v.y, lane + 1);
        if (lane == 0)  { lz = 0.f; lw = 0.f; }
        if (lane == 63) { rx = 0.f; ry = 0.f; }
        float4 hv;
        hv.x = fmaf(g, lz,  fmaf(G, lw,  fmaf(G, v.y, fmaf(g, v.z, v.x))));
        hv.y = fmaf(g, lw,  fmaf(G, v.x, fmaf(G, v.z, fmaf(g, v.w, v.y))));
        hv.z = fmaf(g, v.x, fmaf(G, v.y, fmaf(G, v.w, fmaf(g, rx, v.z))));
        hv.w = fmaf(g, v.y, fmaf(G, v.z, fmaf(G, rx,  fmaf(g, ry, v.w))));
        h0 = h1; h1 = h2; h2 = h3; h3 = h4; h4 = hv;

        if (j >= r0 + 1) {
            // vertical gaussian -> smoothed row m = j-2
            float4 sv;
            sv.x = (g * (h0.x + h4.x) + G * (h1.x + h3.x) + h2.x) * inv2;
            sv.y = (g * (h0.y + h4.y) + G * (h1.y + h3.y) + h2.y) * inv2;
            sv.z = (g * (h0.z + h4.z) + G * (h1.z + h3.z) + h2.z) * inv2;
            sv.w = (g * (h0.w + h4.w) + G * (h1.w + h3.w) + h2.w) * inv2;
            s0 = s1; s1 = s2; s2 = sv;

            if (j >= r0 + 3) {
                const int er = j - 3;            // edge row in [r0, r0+15]
                float4 A = s0, B = s1, C = s2;   // rows er-1, er, er+1 of sm
                float Alw = __shfl(A.w, lane - 1), Arx = __shfl(A.x, lane + 1);
                float Blw = __shfl(B.w, lane - 1), Brx = __shfl(B.x, lane + 1);
                float Clw = __shfl(C.w, lane - 1), Crx = __shfl(C.x, lane + 1);
                if (lane == 0)  { Alw = 0.f; Blw = 0.f; Clw = 0.f; }
                if (lane == 63) { Arx = 0.f; Brx = 0.f; Crx = 0.f; }
                if (er == 0)   { A = float4{}; Alw = 0.f; Arx = 0.f; }  // sm zero-pad
                if (er == 255) { C = float4{}; Clw = 0.f; Crx = 0.f; }
                float A6[6] = {Alw, A.x, A.y, A.z, A.w, Arx};
                float B6[6] = {Blw, B.x, B.y, B.z, B.w, Brx};
                float C6[6] = {Clw, C.x, C.y, C.z, C.w, Crx};
                float4 e4;
                float* ev = (float*)&e4;
#pragma unroll
                for (int k = 0; k < 4; ++k) {
                    float g0  = 3.f * (A6[k] - A6[k+2]) + 10.f * (B6[k] - B6[k+2])
                              + 3.f * (C6[k] - C6[k+2]);
                    float g90 = 3.f * (A6[k] - C6[k]) + 10.f * (A6[k+1] - C6[k+1])
                              + 3.f * (A6[k+2] - C6[k+2]);
                    float lap = 4.f * B6[k+1] - B6[k] - B6[k+2] - A6[k+1] - C6[k+1];
                    float e = fmaxf(fabsf(g0), fabsf(g90)) + 0.1f * fabsf(lap);
                    ev[k] = e;
                    lmax = fmaxf(lmax, e);
                    lsum += e;
                }
                *(float4*)(ep + er * 256 + col4) = e4;
            }
        }
        vcur = vnext;
    }

    for (int off = 32; off > 0; off >>= 1) {
        lmax = fmaxf(lmax, __shfl_down(lmax, off));
        lsum += __shfl_down(lsum, off);
    }
    if (lane == 0) {
        wavemax[task] = lmax;
        wavesum[task] = lsum;
    }
}

__global__ __launch_bounds__(256) void k3_se(const float* __restrict__ wavemax,
                                             const float* __restrict__ wavesum,
                                             const float* __restrict__ w_fc1,
                                             const float* __restrict__ b_fc1,
                                             const float* __restrict__ w_fc2,
                                             const float* __restrict__ b_fc2,
                                             const float* __restrict__ w_out,
                                             float* __restrict__ w_eff) {
    const int tid = threadIdx.x;
    const int b = tid >> 6, o = tid & 63;
    __shared__ float smax[256];
    __shared__ float ssum[256];   // per-plane sums (plane = tid)
    __shared__ float coef[256];   // scale[b][c] * inv

    // reduce global max over 4096 wave maxima
    float m = 0.f;
    for (int i = tid; i < 4096; i += 256) m = fmaxf(m, wavemax[i]);
    smax[tid] = m;
    // per-plane sum of 16 band sums (deterministic order)
    float ps = 0.f;
#pragma unroll
    for (int k = 0; k < 16; ++k) ps += wavesum[tid * 16 + k];
    ssum[tid] = ps;
    __syncthreads();
    for (int s = 128; s > 0; s >>= 1) {
        if (tid < s) smax[tid] = fmaxf(smax[tid], smax[tid + s]);
        __syncthreads();
    }
    const float mx = smax[0];
    const float inv = 1.f / (mx + 1e-8f);

    float h[4];
#pragma unroll
    for (int j = 0; j < 4; ++j) h[j] = b_fc1[j];
    for (int c = 0; c < 64; ++c) {
        float pooled = ssum[b * 64 + c] * inv * (1.f / 65536.f);
#pragma unroll
        for (int j = 0; j < 4; ++j) h[j] = fmaf(pooled, w_fc1[j * 64 + c], h[j]);
    }
#pragma unroll
    for (int j = 0; j < 4; ++j) h[j] = fmaxf(h[j], 0.f);
    float z = b_fc2[o];
#pragma unroll
    for (int j = 0; j < 4; ++j) z = fmaf(h[j], w_fc2[o * 4 + j], z);
    float sc = 1.f / (1.f + expf(-z));
    coef[tid] = sc * inv;
    __syncthreads();
    // w_eff[b][c][o] = w_out[o][c] * coef[b][c]
    for (int c = 0; c < 64; ++c)
        w_eff[((b * 64) + c) * 64 + o] = w_out[o * 64 + c] * coef[b * 64 + c];
}

// conv1x1 64->64, per-batch folded weights via s_load; edge ring depth 8.
__global__ __launch_bounds__(256) void k4_out(const float* __restrict__ edge,
                                              const float* __restrict__ w_eff,
                                              const float* __restrict__ b_out,
                                              float* __restrict__ out) {
    const int tid  = threadIdx.x;
    const int lane = tid & 63;
    const int og   = __builtin_amdgcn_readfirstlane((tid >> 6) << 4);
    const int blk  = blockIdx.x;
    const int b    = blk >> 8;
    const int px   = ((blk & 255) << 8) + (lane << 2);

    const float* eb  = edge + (size_t)(b << 6) * HW + px;
    const float* wTg = w_eff + (b << 12) + og;    // uniform base

    float acc[4][16];
#pragma unroll
    for (int oi = 0; oi < 16; ++oi) {
        float bv = b_out[og + oi];
        acc[0][oi] = bv; acc[1][oi] = bv; acc[2][oi] = bv; acc[3][oi] = bv;
    }

    float4 xr0 = *(const float4*)(eb + 0 * (size_t)HW);
    float4 xr1 = *(const float4*)(eb + 1 * (size_t)HW);
    float4 xr2 = *(const float4*)(eb + 2 * (size_t)HW);
    float4 xr3 = *(const float4*)(eb + 3 * (size_t)HW);
    float4 xr4 = *(const float4*)(eb + 4 * (size_t)HW);
    float4 xr5 = *(const float4*)(eb + 5 * (size_t)HW);
    float4 xr6 = *(const float4*)(eb + 6 * (size_t)HW);
    float4 xr7 = *(const float4*)(eb + 7 * (size_t)HW);

#pragma unroll 1
    for (int cc = 0; cc < 64; cc += 8) {
        {
            const int gn = (cc + 8) & 63;
            float4 n0 = *(const float4*)(eb + (size_t)(gn    ) * HW);
            float4 n1 = *(const float4*)(eb + (size_t)(gn + 1) * HW);
            float4 n2 = *(const float4*)(eb + (size_t)(gn + 2) * HW);
            float4 n3 = *(const float4*)(eb + (size_t)(gn + 3) * HW);
            CH_COMP(xr0, wTg + (size_t)(cc    ) * 64);
            CH_COMP(xr1, wTg + (size_t)(cc + 1) * 64);
            CH_COMP(xr2, wTg + (size_t)(cc + 2) * 64);
            CH_COMP(xr3, wTg + (size_t)(cc + 3) * 64);
            xr0 = n0; xr1 = n1; xr2 = n2; xr3 = n3;
        }
        {
            const int gn = (cc + 12) & 63;
            float4 n0 = *(const float4*)(eb + (size_t)(gn    ) * HW);
            float4 n1 = *(const float4*)(eb + (size_t)(gn + 1) * HW);
            float4 n2 = *(const float4*)(eb + (size_t)(gn + 2) * HW);
            float4 n3 = *(const float4*)(eb + (size_t)(gn + 3) * HW);
            CH_COMP(xr4, wTg + (size_t)(cc + 4) * 64);
            CH_COMP(xr5, wTg + (size_t)(cc + 5) * 64);
            CH_COMP(xr6, wTg + (size_t)(cc + 6) * 64);
            CH_COMP(xr7, wTg + (size_t)(cc + 7) * 64);
            xr4 = n0; xr5 = n1; xr6 = n2; xr7 = n3;
        }
    }

    float* ob = out + (size_t)(b << 6) * HW + px;
#pragma unroll
    for (int oi = 0; oi < 16; ++oi)
        *(float4*)(ob + (size_t)(og + oi) * HW) = float4{acc[0][oi], acc[1][oi],
                                                         acc[2][oi], acc[3][oi]};
}

extern "C" void kernel_launch(void* const* d_in, const int* in_sizes, int n_in,
                              void* d_out, int out_size, void* d_ws, size_t ws_size,
                              hipStream_t stream) {
    const float* x     = (const float*)d_in[0];
    const float* w_in  = (const float*)d_in[1];
    const float* b_in  = (const float*)d_in[2];
    const float* w_fc1 = (const float*)d_in[3];
    const float* b_fc1 = (const float*)d_in[4];
    const float* w_fc2 = (const float*)d_in[5];
    const float* b_fc2 = (const float*)d_in[6];
    const float* w_out = (const float*)d_in[7];
    const float* b_out = (const float*)d_in[8];

    char* ws = (char*)d_ws;
    float* wT      = (float*)(ws + WS_WT);
    float* y       = (float*)(ws + WS_Y);
    float* edge    = (float*)(ws + WS_EDGE);
    float* wavemax = (float*)(ws + WS_SMALL);            // 4096 floats
    float* wavesum = (float*)(ws + WS_SMALL + 16384);    // 4096 floats
    float* w_eff   = (float*)(ws + WS_SMALL + 32768);    // 4*64*64 floats
    float* out     = (float*)d_out;

    hipLaunchKernelGGL(k0_prep,  dim3(1),    dim3(256), 0, stream, w_in, wT);
    hipLaunchKernelGGL(k1_convin,dim3(1024), dim3(256), 0, stream, x, wT, b_in, y);
    hipLaunchKernelGGL(k2_edge,  dim3(1024), dim3(256), 0, stream, y, edge, wavemax, wavesum);
    hipLaunchKernelGGL(k3_se,    dim3(1),    dim3(256), 0, stream, wavemax, wavesum,
                       w_fc1, b_fc1, w_fc2, b_fc2, w_out, w_eff);
    hipLaunchKernelGGL(k4_out,   dim3(1024), dim3(256), 0, stream, edge, w_eff, b_out, out);
}